// Round 3
// baseline (205.381 us; speedup 1.0000x reference)
//
#include <hip/hip_runtime.h>

#define NB 32
#define LL 2048
#define CH 512
#define BQ 512
#define HH 1024
#define LDA 520   // LDS row stride (bf16 elems): +8 pad -> ~1 conflict/read (measured r1)

typedef __attribute__((ext_vector_type(8))) short bf16x8;
typedef __attribute__((ext_vector_type(16))) float f32x16;

__device__ __forceinline__ unsigned short f2bf(float x) {
  unsigned int u = __float_as_uint(x);
  u += 0x7FFFu + ((u >> 16) & 1u);   // round-to-nearest-even
  return (unsigned short)(u >> 16);
}

__device__ __forceinline__ float fast_tanh(float x) {
  // tanh(x) = 1 - 2/(e^{2x}+1); saturates correctly at +-inf
  float e = __expf(2.0f * x);
  return 1.0f - 2.0f * __builtin_amdgcn_rcpf(e + 1.0f);
}

// ---------------- res_qc[b][h] = query[b,:]·Wq[h,:] + bc[h] ----------------
__global__ __launch_bounds__(256) void k_resqc(const float* __restrict__ query,
                                               const float* __restrict__ Wq,
                                               const float* __restrict__ bc,
                                               float* __restrict__ resqc) {
  int gid = blockIdx.x * 256 + threadIdx.x;   // 32768
  int b = gid >> 10, h = gid & 1023;
  const float4* q4 = (const float4*)(query + (size_t)b * BQ);
  const float4* w4 = (const float4*)(Wq + (size_t)h * BQ);
  float acc = 0.f;
#pragma unroll 4
  for (int i = 0; i < BQ / 4; ++i) {
    float4 a = q4[i], w = w4[i];
    acc += a.x * w.x + a.y * w.y + a.z * w.z + a.w * w.w;
  }
  resqc[gid] = acc + bc[h];
}

// ---------------- Wc f32 -> bf16 ----------------
__global__ __launch_bounds__(256) void k_cvt_wc(const float* __restrict__ Wc,
                                                unsigned short* __restrict__ wcb) {
  int f = blockIdx.x * 256 + threadIdx.x;   // float4 idx, 131072 total
  float4 v = ((const float4*)Wc)[f];
  union { unsigned short s[4]; uint2 u; } p;
  p.s[0] = f2bf(v.x); p.s[1] = f2bf(v.y); p.s[2] = f2bf(v.z); p.s[3] = f2bf(v.w);
  ((uint2*)wcb)[f] = p.u;
}

// ---------------- main: part[hh][b][l] = sum_{h in half hh} Wo[h]*tanh(resqc[b][h] + ctx[b,l,:]·Wc[h,:])
// 2048 blocks = 1024 l-tiles x 2 h-halves. 512 threads = 8 waves.
// Wave owns 64 cols (2 col-frags) x 64 rows (2 row-frags) -> acc 64 VGPR.
// A (ctx tile, bf16) in padded LDS; B (wcb) streamed global->reg, 2-deep dbuf.
__global__ __launch_bounds__(512, 4) void k_logits(const float* __restrict__ ctx,
                                                   const unsigned short* __restrict__ wcb,
                                                   const float* __restrict__ resqc,
                                                   const float* __restrict__ Wo,
                                                   float* __restrict__ part) {
  __shared__ unsigned short Alds[64 * LDA];   // 66560 B
  __shared__ float lsum[64];

  int t = threadIdx.x;
  int bid = blockIdx.x;
  // XCD pair-swizzle: both hh-halves of one l-tile land consecutively on one XCD
  int swz = (bid & 7) * 256 + (bid >> 3);
  int lt = swz >> 1, hh = swz & 1;
  int b = lt >> 5;                 // 32 l-tiles per batch
  int row0 = (lt & 31) << 6;

  if (t < 64) lsum[t] = 0.f;

  // stage 64x512 f32 -> bf16 LDS (padded rows). 512 thr x 16 float4.
  const float4* src = (const float4*)(ctx + ((size_t)(b * LL + row0)) * CH);
#pragma unroll
  for (int p = 0; p < 16; ++p) {
    int f = p * 512 + t;
    int r = f >> 7, c4 = f & 127;
    float4 v = src[f];
    union { unsigned short s[4]; uint2 u; } pk;
    pk.s[0] = f2bf(v.x); pk.s[1] = f2bf(v.y); pk.s[2] = f2bf(v.z); pk.s[3] = f2bf(v.w);
    *(uint2*)(Alds + r * LDA + c4 * 4) = pk.u;
  }
  __syncthreads();

  int wave = t >> 6, lane = t & 63;
  int lo = lane & 31, hi = lane >> 5;

  const char* a0b = (const char*)Alds + lo * (LDA * 2) + hi * 16;
  const char* a1b = a0b + 32 * (LDA * 2);

  int n0 = hh * 512 + wave * 64;   // this wave's 64 cols
  const char* pB0 = (const char*)(wcb + (size_t)(n0 + lo) * CH) + hi * 16;
  const char* pB1 = (const char*)(wcb + (size_t)(n0 + 32 + lo) * CH) + hi * 16;

  f32x16 acc00 = {0,0,0,0,0,0,0,0,0,0,0,0,0,0,0,0};
  f32x16 acc01 = {0,0,0,0,0,0,0,0,0,0,0,0,0,0,0,0};
  f32x16 acc10 = {0,0,0,0,0,0,0,0,0,0,0,0,0,0,0,0};
  f32x16 acc11 = {0,0,0,0,0,0,0,0,0,0,0,0,0,0,0,0};

  // 2-deep register double-buffer over ks-pairs (16 groups of 2 ks). Fully
  // unrolled -> all buffer indices static (no scratch), loads issued one
  // group ahead of use (~500 cyc at 4 waves/SIMD -> covers L2 latency).
  bf16x8 rbA[2][2], rbB[2][2];
#pragma unroll
  for (int j = 0; j < 2; ++j) {
    rbA[0][j] = *(const bf16x8*)(pB0 + j * 32);
    rbB[0][j] = *(const bf16x8*)(pB1 + j * 32);
  }
#pragma unroll
  for (int g = 0; g < 16; ++g) {
    int cur = g & 1, nxt = cur ^ 1;
    if (g < 15) {
#pragma unroll
      for (int j = 0; j < 2; ++j) {
        rbA[nxt][j] = *(const bf16x8*)(pB0 + (size_t)(g * 2 + 2 + j) * 32);
        rbB[nxt][j] = *(const bf16x8*)(pB1 + (size_t)(g * 2 + 2 + j) * 32);
      }
    }
#pragma unroll
    for (int j = 0; j < 2; ++j) {
      int ks = g * 2 + j;
      bf16x8 fa0 = *(const bf16x8*)(a0b + ks * 32);
      bf16x8 fa1 = *(const bf16x8*)(a1b + ks * 32);
      acc00 = __builtin_amdgcn_mfma_f32_32x32x16_bf16(fa0, rbA[cur][j], acc00, 0, 0, 0);
      acc01 = __builtin_amdgcn_mfma_f32_32x32x16_bf16(fa0, rbB[cur][j], acc01, 0, 0, 0);
      acc10 = __builtin_amdgcn_mfma_f32_32x32x16_bf16(fa1, rbA[cur][j], acc10, 0, 0, 0);
      acc11 = __builtin_amdgcn_mfma_f32_32x32x16_bf16(fa1, rbB[cur][j], acc11, 0, 0, 0);
    }
  }

  float qA = resqc[b * HH + n0 + lo], qB = resqc[b * HH + n0 + 32 + lo];
  float wA = Wo[n0 + lo],             wB = Wo[n0 + 32 + lo];
  float p0[16], p1[16];
#pragma unroll
  for (int r = 0; r < 16; ++r) {
    p0[r] = wA * fast_tanh(acc00[r] + qA) + wB * fast_tanh(acc01[r] + qB);
    p1[r] = wA * fast_tanh(acc10[r] + qA) + wB * fast_tanh(acc11[r] + qB);
  }
  // butterfly over the 32-lane halves (cols); rows stay lane-local
#pragma unroll
  for (int m = 16; m >= 1; m >>= 1) {
#pragma unroll
    for (int r = 0; r < 16; ++r) {
      p0[r] += __shfl_xor(p0[r], m, 64);
      p1[r] += __shfl_xor(p1[r], m, 64);
    }
  }
  if (lo == 0) {
#pragma unroll
    for (int r = 0; r < 16; ++r) {
      int row_a = (r & 3) + 8 * (r >> 2) + 4 * hi;   // verified 32x32 C/D row map
      atomicAdd(&lsum[row_a], p0[r]);
      atomicAdd(&lsum[32 + row_a], p1[r]);
    }
  }
  __syncthreads();
  if (t < 64) part[(size_t)hh * NB * LL + (size_t)b * LL + row0 + t] = lsum[t];
}

// ---------------- weights: mask*exp(part0+part1+bo), normalize over L ----------------
__global__ __launch_bounds__(256) void k_weights(const float* __restrict__ mask,
                                                 const float* __restrict__ bo,
                                                 const float* __restrict__ part,
                                                 float* __restrict__ wout) {
  __shared__ float red[4];
  int b = blockIdx.x, t = threadIdx.x;
  float bov = bo[0];
  float w[8];
  float s = 0.f;
#pragma unroll
  for (int i = 0; i < 8; ++i) {
    int l = t + 256 * i;
    float lg = part[b * LL + l] + part[NB * LL + b * LL + l] + bov;
    float e = mask[b * LL + l] * __expf(lg);
    w[i] = e; s += e;
  }
#pragma unroll
  for (int m = 32; m >= 1; m >>= 1) s += __shfl_xor(s, m, 64);
  int wave = t >> 6, lane = t & 63;
  if (lane == 0) red[wave] = s;
  __syncthreads();
  float inv = 1.0f / (red[0] + red[1] + red[2] + red[3] + 1e-5f);
#pragma unroll
  for (int i = 0; i < 8; ++i) wout[b * LL + t + 256 * i] = w[i] * inv;
}

// ---------------- output[b][c] = sum_l weights[b][l] * ctx[b][l][c] ----------------
__global__ __launch_bounds__(256) void k_output(const float* __restrict__ ctx,
                                                const float* __restrict__ weights,
                                                float* __restrict__ out) {
  __shared__ float wl[128];
  int bid = blockIdx.x;            // 512 = 32 b * 16 chunks
  int b = bid >> 4, chunk = bid & 15;
  int t = threadIdx.x;
  int l0 = chunk * 128;
  if (t < 128) wl[t] = weights[b * LL + l0 + t];
  __syncthreads();
  const float2* c2 = (const float2*)(ctx + ((size_t)(b * LL + l0)) * CH) + t;
  float ax = 0.f, ay = 0.f;
#pragma unroll 4
  for (int l = 0; l < 128; ++l) {
    float wv = wl[l];
    float2 v = c2[(size_t)l * (CH / 2)];
    ax += wv * v.x; ay += wv * v.y;
  }
  atomicAdd(&out[b * CH + 2 * t], ax);
  atomicAdd(&out[b * CH + 2 * t + 1], ay);
}

extern "C" void kernel_launch(void* const* d_in, const int* in_sizes, int n_in,
                              void* d_out, int out_size, void* d_ws, size_t ws_size,
                              hipStream_t stream) {
  const float* query = (const float*)d_in[0];
  const float* ctx   = (const float*)d_in[1];
  const float* mask  = (const float*)d_in[2];
  const float* Wq    = (const float*)d_in[3];
  const float* Wc    = (const float*)d_in[4];
  const float* bc    = (const float*)d_in[5];
  const float* Wo    = (const float*)d_in[6];
  const float* bo    = (const float*)d_in[7];
  float* out = (float*)d_out;

  unsigned short* wcb = (unsigned short*)d_ws;                    // 1 MB bf16 Wc
  float* resqc = (float*)((char*)d_ws + (1 << 20));               // 128 KB
  float* part  = (float*)((char*)d_ws + (1 << 20) + (1 << 17));   // 2 x 32 x 2048 f32 = 512 KB
  float* wout = out + NB * CH;                                    // final weights slot

  hipMemsetAsync(out, 0, NB * CH * sizeof(float), stream);        // zero output region
  k_resqc<<<128, 256, 0, stream>>>(query, Wq, bc, resqc);
  k_cvt_wc<<<512, 256, 0, stream>>>(Wc, wcb);
  k_logits<<<2048, 512, 0, stream>>>(ctx, wcb, resqc, Wo, part);
  k_weights<<<32, 256, 0, stream>>>(mask, bo, part, wout);
  k_output<<<512, 256, 0, stream>>>(ctx, wout, out);
}

// Round 4
// 144.558 us; speedup vs baseline: 1.4207x; 1.4207x over previous
//
#include <hip/hip_runtime.h>

#define NB 32
#define LL 2048
#define CH 512
#define BQ 512
#define HH 1024
#define LDA 520   // LDS row stride (bf16 elems): +8 pad -> 2-way (free) on b128 reads

typedef __attribute__((ext_vector_type(8))) short bf16x8;
typedef __attribute__((ext_vector_type(16))) float f32x16;

__device__ __forceinline__ unsigned short f2bf(float x) {
  unsigned int u = __float_as_uint(x);
  u += 0x7FFFu + ((u >> 16) & 1u);   // round-to-nearest-even
  return (unsigned short)(u >> 16);
}

__device__ __forceinline__ float fast_tanh(float x) {
  // tanh(x) = 1 - 2/(e^{2x}+1); saturates correctly at +-inf
  float e = __expf(2.0f * x);
  return 1.0f - 2.0f * __builtin_amdgcn_rcpf(e + 1.0f);
}

// ---------------- res_qc[b][h] = query[b,:]·Wq[h,:] + bc[h] ----------------
__global__ __launch_bounds__(256) void k_resqc(const float* __restrict__ query,
                                               const float* __restrict__ Wq,
                                               const float* __restrict__ bc,
                                               float* __restrict__ resqc) {
  int gid = blockIdx.x * 256 + threadIdx.x;   // 32768
  int b = gid >> 10, h = gid & 1023;
  const float4* q4 = (const float4*)(query + (size_t)b * BQ);
  const float4* w4 = (const float4*)(Wq + (size_t)h * BQ);
  float acc = 0.f;
#pragma unroll 4
  for (int i = 0; i < BQ / 4; ++i) {
    float4 a = q4[i], w = w4[i];
    acc += a.x * w.x + a.y * w.y + a.z * w.z + a.w * w.w;
  }
  resqc[gid] = acc + bc[h];
}

// ---------------- Wc f32 -> bf16, packed in MFMA B-fragment order ----------------
// wcbp[cg][ks][lane][8] : lane=(lo,hi) gets Wc[cg*32+lo][hi*8 + ks*16 .. +8]
// -> a wave's B-frag load for (cg,ks) is 1024 contiguous bytes (coalesced).
__global__ __launch_bounds__(256) void k_pack_wc(const float* __restrict__ Wc,
                                                 unsigned short* __restrict__ wcbp) {
  int gid = blockIdx.x * 256 + threadIdx.x;   // 65536 = 32 cg * 32 ks * 64 lanes
  int lane = gid & 63, ks = (gid >> 6) & 31, cg = gid >> 11;
  int lo = lane & 31, hi = lane >> 5;
  const float4* s = (const float4*)(Wc + (size_t)(cg * 32 + lo) * CH + hi * 8 + ks * 16);
  float4 v0 = s[0], v1 = s[1];
  union { unsigned short s[8]; uint4 u; } p;
  p.s[0] = f2bf(v0.x); p.s[1] = f2bf(v0.y); p.s[2] = f2bf(v0.z); p.s[3] = f2bf(v0.w);
  p.s[4] = f2bf(v1.x); p.s[5] = f2bf(v1.y); p.s[6] = f2bf(v1.z); p.s[7] = f2bf(v1.w);
  ((uint4*)wcbp)[gid] = p.u;
}

// ---------------- main: part[hh][b][l] = sum_{h in half hh} Wo[h]*tanh(resqc[b][h] + ctx[b,l,:]·Wc[h,:])
// 2048 blocks = 1024 l-tiles x 2 h-halves. 512 threads = 8 waves.
// Wave owns 64 cols (2 col-frags) x 64 rows (2 row-frags) -> acc 64 regs.
// A (ctx tile, bf16) in padded LDS; B from packed wcbp, coalesced 1KB/wave loads.
__global__ __launch_bounds__(512, 4) void k_logits(const float* __restrict__ ctx,
                                                   const unsigned short* __restrict__ wcbp,
                                                   const float* __restrict__ resqc,
                                                   const float* __restrict__ Wo,
                                                   float* __restrict__ part) {
  __shared__ unsigned short Alds[64 * LDA];   // 66560 B
  __shared__ float lsum[64];

  int t = threadIdx.x;
  int bid = blockIdx.x;
  // XCD pair-swizzle: both hh-halves of one l-tile land consecutively on one XCD
  int swz = (bid & 7) * 256 + (bid >> 3);
  int lt = swz >> 1, hh = swz & 1;
  int b = lt >> 5;                 // 32 l-tiles per batch
  int row0 = (lt & 31) << 6;

  if (t < 64) lsum[t] = 0.f;

  // stage 64x512 f32 -> bf16 LDS (padded rows). 512 thr x 16 float4.
  const float4* src = (const float4*)(ctx + ((size_t)(b * LL + row0)) * CH);
#pragma unroll
  for (int p = 0; p < 16; ++p) {
    int f = p * 512 + t;
    int r = f >> 7, c4 = f & 127;
    float4 v = src[f];
    union { unsigned short s[4]; uint2 u; } pk;
    pk.s[0] = f2bf(v.x); pk.s[1] = f2bf(v.y); pk.s[2] = f2bf(v.z); pk.s[3] = f2bf(v.w);
    *(uint2*)(Alds + r * LDA + c4 * 4) = pk.u;
  }
  __syncthreads();

  int wave = t >> 6, lane = t & 63;
  int lo = lane & 31, hi = lane >> 5;

  const char* a0b = (const char*)Alds + lo * (LDA * 2) + hi * 16;
  const char* a1b = a0b + 32 * (LDA * 2);

  int n0 = hh * 512 + wave * 64;   // this wave's 64 cols
  int cg0 = n0 >> 5;               // 32-col fragment groups
  const uint4* bp0 = (const uint4*)wcbp + (size_t)(cg0 * 32) * 64 + lane;
  const uint4* bp1 = (const uint4*)wcbp + (size_t)((cg0 + 1) * 32) * 64 + lane;

  f32x16 acc00 = {0,0,0,0,0,0,0,0,0,0,0,0,0,0,0,0};
  f32x16 acc01 = {0,0,0,0,0,0,0,0,0,0,0,0,0,0,0,0};
  f32x16 acc10 = {0,0,0,0,0,0,0,0,0,0,0,0,0,0,0,0};
  f32x16 acc11 = {0,0,0,0,0,0,0,0,0,0,0,0,0,0,0,0};

#pragma unroll 8
  for (int ks = 0; ks < 32; ++ks) {           // K = 512 / 16
    uint4 ub0 = bp0[ks * 64];
    uint4 ub1 = bp1[ks * 64];
    bf16x8 fa0 = *(const bf16x8*)(a0b + ks * 32);
    bf16x8 fa1 = *(const bf16x8*)(a1b + ks * 32);
    bf16x8 fb0, fb1;
    __builtin_memcpy(&fb0, &ub0, 16);
    __builtin_memcpy(&fb1, &ub1, 16);
    acc00 = __builtin_amdgcn_mfma_f32_32x32x16_bf16(fa0, fb0, acc00, 0, 0, 0);
    acc01 = __builtin_amdgcn_mfma_f32_32x32x16_bf16(fa0, fb1, acc01, 0, 0, 0);
    acc10 = __builtin_amdgcn_mfma_f32_32x32x16_bf16(fa1, fb0, acc10, 0, 0, 0);
    acc11 = __builtin_amdgcn_mfma_f32_32x32x16_bf16(fa1, fb1, acc11, 0, 0, 0);
  }

  float qA = resqc[b * HH + n0 + lo], qB = resqc[b * HH + n0 + 32 + lo];
  float wA = Wo[n0 + lo],             wB = Wo[n0 + 32 + lo];
  float p0[16], p1[16];
#pragma unroll
  for (int r = 0; r < 16; ++r) {
    p0[r] = wA * fast_tanh(acc00[r] + qA) + wB * fast_tanh(acc01[r] + qB);
    p1[r] = wA * fast_tanh(acc10[r] + qA) + wB * fast_tanh(acc11[r] + qB);
  }
  // butterfly over the 32-lane halves (cols); rows stay lane-local
#pragma unroll
  for (int m = 16; m >= 1; m >>= 1) {
#pragma unroll
    for (int r = 0; r < 16; ++r) {
      p0[r] += __shfl_xor(p0[r], m, 64);
      p1[r] += __shfl_xor(p1[r], m, 64);
    }
  }
  if (lo == 0) {
#pragma unroll
    for (int r = 0; r < 16; ++r) {
      int row_a = (r & 3) + 8 * (r >> 2) + 4 * hi;   // verified 32x32 C/D row map
      atomicAdd(&lsum[row_a], p0[r]);
      atomicAdd(&lsum[32 + row_a], p1[r]);
    }
  }
  __syncthreads();
  if (t < 64) part[(size_t)hh * NB * LL + (size_t)b * LL + row0 + t] = lsum[t];
}

// ---------------- weights: mask*exp(part0+part1+bo), normalize over L ----------------
__global__ __launch_bounds__(256) void k_weights(const float* __restrict__ mask,
                                                 const float* __restrict__ bo,
                                                 const float* __restrict__ part,
                                                 float* __restrict__ wout) {
  __shared__ float red[4];
  int b = blockIdx.x, t = threadIdx.x;
  float bov = bo[0];
  float w[8];
  float s = 0.f;
#pragma unroll
  for (int i = 0; i < 8; ++i) {
    int l = t + 256 * i;
    float lg = part[b * LL + l] + part[NB * LL + b * LL + l] + bov;
    float e = mask[b * LL + l] * __expf(lg);
    w[i] = e; s += e;
  }
#pragma unroll
  for (int m = 32; m >= 1; m >>= 1) s += __shfl_xor(s, m, 64);
  int wave = t >> 6, lane = t & 63;
  if (lane == 0) red[wave] = s;
  __syncthreads();
  float inv = 1.0f / (red[0] + red[1] + red[2] + red[3] + 1e-5f);
#pragma unroll
  for (int i = 0; i < 8; ++i) wout[b * LL + t + 256 * i] = w[i] * inv;
}

// ---------------- output[b][c] = sum_l weights[b][l] * ctx[b][l][c] ----------------
__global__ __launch_bounds__(256) void k_output(const float* __restrict__ ctx,
                                                const float* __restrict__ weights,
                                                float* __restrict__ out) {
  __shared__ float wl[128];
  int bid = blockIdx.x;            // 512 = 32 b * 16 chunks
  int b = bid >> 4, chunk = bid & 15;
  int t = threadIdx.x;
  int l0 = chunk * 128;
  if (t < 128) wl[t] = weights[b * LL + l0 + t];
  __syncthreads();
  const float2* c2 = (const float2*)(ctx + ((size_t)(b * LL + l0)) * CH) + t;
  float ax = 0.f, ay = 0.f;
#pragma unroll 4
  for (int l = 0; l < 128; ++l) {
    float wv = wl[l];
    float2 v = c2[(size_t)l * (CH / 2)];
    ax += wv * v.x; ay += wv * v.y;
  }
  atomicAdd(&out[b * CH + 2 * t], ax);
  atomicAdd(&out[b * CH + 2 * t + 1], ay);
}

extern "C" void kernel_launch(void* const* d_in, const int* in_sizes, int n_in,
                              void* d_out, int out_size, void* d_ws, size_t ws_size,
                              hipStream_t stream) {
  const float* query = (const float*)d_in[0];
  const float* ctx   = (const float*)d_in[1];
  const float* mask  = (const float*)d_in[2];
  const float* Wq    = (const float*)d_in[3];
  const float* Wc    = (const float*)d_in[4];
  const float* bc    = (const float*)d_in[5];
  const float* Wo    = (const float*)d_in[6];
  const float* bo    = (const float*)d_in[7];
  float* out = (float*)d_out;

  unsigned short* wcbp = (unsigned short*)d_ws;                   // 1 MB packed bf16 Wc
  float* resqc = (float*)((char*)d_ws + (1 << 20));               // 128 KB
  float* part  = (float*)((char*)d_ws + (1 << 20) + (1 << 17));   // 2 x 32 x 2048 f32 = 512 KB
  float* wout = out + NB * CH;                                    // final weights slot

  hipMemsetAsync(out, 0, NB * CH * sizeof(float), stream);        // zero output region
  k_resqc<<<128, 256, 0, stream>>>(query, Wq, bc, resqc);
  k_pack_wc<<<256, 256, 0, stream>>>(Wc, wcbp);
  k_logits<<<2048, 512, 0, stream>>>(ctx, wcbp, resqc, Wo, part);
  k_weights<<<32, 256, 0, stream>>>(mask, bo, part, wout);
  k_output<<<512, 256, 0, stream>>>(ctx, wout, out);
}